// Round 9
// baseline (226.282 us; speedup 1.0000x reference)
//
#include <hip/hip_runtime.h>
#include <math.h>

#define N_   128
#define H_   400
#define W_   400
#define MS_  28
#define CT_  80
#define CS_  53
#define HW_  (H_*W_)
#define NCH_ (CS_ + N_)   // 181
#define WG_  1600
#define IGN_ 255
#define G_   8            // channel groups (power of 2!)
#define CPG_ 23           // ceil(181/8)
#define PPT_ 4            // pixels per thread (float4)
#define BT_  256          // threads per block
#define PPB_ (BT_*PPT_)   // 1024 pixels per block
#define GX_  ((HW_ + PPB_ - 1)/PPB_)   // 157

typedef float f4 __attribute__((ext_vector_type(4)));
typedef unsigned long long u64;

struct NParam {
  int vy_lo, vy_hi, vx_lo, vx_hi;   // mask-valid box (inclusive)
  int cy1, cy2, cx1, cx2;           // sem box (y in [cy1,cy2), x in [cx1,cx2))
  float sy, sx;                     // 28/hh, 28/ww
  int y0b, x0b;                     // floor(bbox/4)
  int mlbase, thbase;               // offsets into mask_logits / thing_logit
  int pad0, pad1;                   // 64 B
};

// Device globals. Tickets are EPOCH counters (monotonic, old%G picks the
// winner) -> no zeroing needed, graph-replay and rocprof-replay safe.
// g_lp2/g_vt/g_part are fully rewritten each launch before being read, and
// all cross-block traffic uses agent-scope (cache-bypassing) accesses ->
// no reliance on cross-XCD L2 coherence.
__device__ unsigned int g_tdone[GX_];     // per-tile ticket
__device__ unsigned int g_done;           // global ticket
__device__ u64          g_lp2[(G_*HW_)/2];// per-(group,pixel) LSE m+log(s), packed 2xf32
__device__ float        g_vt[HW_];        // target-channel logit per pixel
__device__ float        g_part[GX_*2];    // per-tile (nll,cnt) partials

static __device__ __forceinline__ u64 pack2(float a, float b) {
  union { float f[2]; u64 u; } t; t.f[0] = a; t.f[1] = b; return t.u;
}
static __device__ __forceinline__ void unpack2(u64 u, float& a, float& b) {
  union { float f[2]; u64 u; } t; t.u = u; a = t.f[0]; b = t.f[1];
}
#define AG_ST(p, v) __hip_atomic_store((p), (v), __ATOMIC_RELAXED, __HIP_MEMORY_SCOPE_AGENT)
#define AG_LD(p)    __hip_atomic_load((p), __ATOMIC_RELAXED, __HIP_MEMORY_SCOPE_AGENT)

__device__ __forceinline__ void lse_update(float v, float& m, float& s) {
  float d = v - m;
  float e = __expf(-fabsf(d));
  s = (d > 0.0f) ? fmaf(s, e, 1.0f) : (s + e);
  m = fmaxf(m, v);
}

// Fused: blockIdx.x = pixel tile (4 px/thread), blockIdx.y = channel group.
// Stuff channels: 4-deep load-pipelined copy+lse (hides LLC latency).
// Thing channels: (1) wave-uniform active bitmask, (2) scalar-branch
// zero-store burst, (3) ctz-walk of active channels with bilinear compute.
// Last group-block per tile (ticket) combines the 8 partial LSEs and reduces
// NLL; last tile-winner overall (ticket) writes the loss.
__global__ __launch_bounds__(256) void main_kernel(
    const float* __restrict__ mask_logits,
    const float* __restrict__ stuff_logit,
    const float* __restrict__ thing_logit,
    const float* __restrict__ bbox,
    const int*   __restrict__ cls_idx,
    const int*   __restrict__ gt,
    float* __restrict__ out)
{
  __shared__ NParam spar[N_];
  __shared__ int4   sbox[N_];   // superbox = union(sem box, mask box), inclusive
  __shared__ float  red[8];
  __shared__ unsigned s_tick, s_fin;
  int tid = threadIdx.x;
  if (tid < N_) {
    int n = tid;
    float b0 = bbox[4*n+0]*0.25f, b1 = bbox[4*n+1]*0.25f,
          b2 = bbox[4*n+2]*0.25f, b3 = bbox[4*n+3]*0.25f;
    int x0b = (int)floorf(b0), y0b = (int)floorf(b1);
    int x2b = (int)floorf(b2), y2b = (int)floorf(b3);
    int hh = y2b - y0b + 1, ww = x2b - x0b + 1;
    NParam p;
    p.vy_lo = max(y0b, 0); p.vy_hi = min(y2b, H_-1);
    p.vx_lo = max(x0b, 0); p.vx_hi = min(x2b, W_-1);
    p.cy1 = (int)b1; p.cx1 = (int)b0;                 // trunc (positive)
    p.cy2 = (int)(rintf(b3) + 1.0f);                  // jnp.round = RNE
    p.cx2 = (int)(rintf(b2) + 1.0f);
    p.sy = 28.0f / (float)hh; p.sx = 28.0f / (float)ww;
    p.y0b = y0b; p.x0b = x0b;
    int cls = cls_idx[n];
    p.mlbase = (n*CT_ + cls)*(MS_*MS_);
    p.thbase = cls*HW_;
    p.pad0 = 0; p.pad1 = 0;
    spar[n] = p;
    sbox[n] = make_int4(min(p.vy_lo, p.cy1), max(p.vy_hi, p.cy2 - 1),
                        min(p.vx_lo, p.cx1), max(p.vx_hi, p.cx2 - 1));
  }
  __syncthreads();

  int pix0 = (blockIdx.x*BT_ + tid)*PPT_;
  bool act = (pix0 < HW_);
  int grp = blockIdx.y;
  int c0 = grp*CPG_;
  int c1 = min(NCH_, c0 + CPG_);

  int y = 0, xb = 0;
  int graw[PPT_];
  #pragma unroll
  for (int k = 0; k < PPT_; ++k) graw[k] = IGN_;

  if (act) {
    y  = pix0 / W_;              // W_ % 4 == 0: all 4 pixels share y
    xb = pix0 - y*W_;

    // target channel per pixel (gt line is cache-hot across the 8 groups)
    int tcs[PPT_];
    #pragma unroll
    for (int k = 0; k < PPT_; ++k) {
      int g = gt[y*(4*WG_) + (xb + k)*4];
      graw[k] = g;
      tcs[k] = min(max(g, 0), NCH_-1);
    }

    float mv[PPT_], sv[PPT_], vts[PPT_];
    #pragma unroll
    for (int k = 0; k < PPT_; ++k) { mv[k] = -INFINITY; sv[k] = 0.0f; vts[k] = 0.0f; }

    // ---- stuff channels: 4-deep load-pipelined copy + lse ----
    // Depth-1 load->store+lse was the latency wall: 23 serial LLC round
    // trips per wave. Chunk by 4 -> 4 independent loads in flight.
    int cs_end = min(c1, CS_);
    int c = c0;
    for (; c + 3 < cs_end; c += 4) {
      f4 v0 = *(const f4*)(stuff_logit + (c+0)*HW_ + pix0);
      f4 v1 = *(const f4*)(stuff_logit + (c+1)*HW_ + pix0);
      f4 v2 = *(const f4*)(stuff_logit + (c+2)*HW_ + pix0);
      f4 v3 = *(const f4*)(stuff_logit + (c+3)*HW_ + pix0);
      *(f4*)(out + (c+0)*HW_ + pix0) = v0;
      *(f4*)(out + (c+1)*HW_ + pix0) = v1;
      *(f4*)(out + (c+2)*HW_ + pix0) = v2;
      *(f4*)(out + (c+3)*HW_ + pix0) = v3;
      #pragma unroll
      for (int k = 0; k < PPT_; ++k) {
        lse_update(v0[k], mv[k], sv[k]);
        lse_update(v1[k], mv[k], sv[k]);
        lse_update(v2[k], mv[k], sv[k]);
        lse_update(v3[k], mv[k], sv[k]);
        if (c+0 == tcs[k]) vts[k] = v0[k];
        if (c+1 == tcs[k]) vts[k] = v1[k];
        if (c+2 == tcs[k]) vts[k] = v2[k];
        if (c+3 == tcs[k]) vts[k] = v3[k];
      }
    }
    for (; c < cs_end; ++c) {
      f4 v = *(const f4*)(stuff_logit + c*HW_ + pix0);
      *(f4*)(out + c*HW_ + pix0) = v;
      #pragma unroll
      for (int k = 0; k < PPT_; ++k) {
        lse_update(v[k], mv[k], sv[k]);
        if (c == tcs[k]) vts[k] = v[k];
      }
    }

    // ---- thing channels: 3-pass (mask / zero-burst / active) ----
    int cth0 = max(c0, CS_);
    int nth  = c1 - cth0;              // 0 for pure-stuff groups
    // Pass 1: wave-uniform active bitmask (no memory traffic)
    unsigned amask = 0u;
    for (int i = 0; i < nth; ++i) {
      int4 u = sbox[cth0 - CS_ + i];
      bool rej = (y < u.x) | (y > u.y) | (xb > u.w) | (xb + PPT_ - 1 < u.z);
      if (!__all(rej)) amask |= (1u << i);
    }
    amask = __builtin_amdgcn_readfirstlane(amask);  // SGPR -> scalar branches
    int zc = nth - __popc(amask);      // wave-uniform
    // Pass 2: dense zero-store burst over rejected channels (scalar branch
    // per iter -> stores fire back-to-back, high store ILP).
    {
      f4 z = {0.0f, 0.0f, 0.0f, 0.0f};
      for (int i = 0; i < nth; ++i) {
        if (!((amask >> i) & 1u))
          *(f4*)(out + (cth0 + i)*HW_ + pix0) = z;
      }
    }
    // Pass 3: active channels only (expected ~1-2 per wave)
    unsigned am = amask;
    while (am) {
      int i = __builtin_ctz(am); am &= am - 1u;
      int cc = cth0 + i;
      int n = cc - CS_;
      NParam p = spar[n];
      float vv[PPT_] = {0.0f, 0.0f, 0.0f, 0.0f};
      if (y >= p.cy1 && y < p.cy2 && xb < p.cx2 && xb+PPT_-1 >= p.cx1) {
        f4 t = *(const f4*)(thing_logit + p.thbase + pix0);
        #pragma unroll
        for (int k = 0; k < PPT_; ++k) {
          int x = xb + k;
          if (x >= p.cx1 && x < p.cx2) vv[k] = t[k];
        }
      }
      if (y >= p.vy_lo && y <= p.vy_hi && xb <= p.vx_hi && xb+PPT_-1 >= p.vx_lo) {
        float srcy = ((float)(y - p.y0b) + 0.5f)*p.sy - 0.5f;
        float fy = floorf(srcy); float ty = srcy - fy;
        int i0 = (int)fminf(fmaxf(fy,        0.0f), (float)(MS_-1));
        int i1 = (int)fminf(fmaxf(fy + 1.0f, 0.0f), (float)(MS_-1));
        const float* r0p = mask_logits + p.mlbase + i0*MS_;
        const float* r1p = mask_logits + p.mlbase + i1*MS_;
        #pragma unroll
        for (int k = 0; k < PPT_; ++k) {
          int x = xb + k;
          if (x >= p.vx_lo && x <= p.vx_hi) {
            float srcx = ((float)(x - p.x0b) + 0.5f)*p.sx - 0.5f;
            float fx = floorf(srcx); float tx = srcx - fx;
            int j0 = (int)fminf(fmaxf(fx,        0.0f), (float)(MS_-1));
            int j1 = (int)fminf(fmaxf(fx + 1.0f, 0.0f), (float)(MS_-1));
            float r0 = r0p[j0]*(1.0f - tx) + r0p[j1]*tx;
            float r1 = r1p[j0]*(1.0f - tx) + r1p[j1]*tx;
            vv[k] += r0*(1.0f - ty) + r1*ty;
          }
        }
      }
      f4 ov = {vv[0], vv[1], vv[2], vv[3]};
      *(f4*)(out + cc*HW_ + pix0) = ov;
      #pragma unroll
      for (int k = 0; k < PPT_; ++k) {
        lse_update(vv[k], mv[k], sv[k]);
        if (cc == tcs[k]) vts[k] = vv[k];
      }
    }

    // merge skipped zero-channels analytically; compress lp = m + log(s)
    float zcf = (float)zc;
    float lpv[PPT_];
    #pragma unroll
    for (int k = 0; k < PPT_; ++k) {
      float m = mv[k], s = sv[k];
      if (zc > 0) {
        if (m >= 0.0f) { s = fmaf(zcf, __expf(-m), s); }
        else           { s = fmaf(s, __expf(m), zcf); m = 0.0f; }  // m=-inf ok: s->zcf
      }
      lpv[k] = m + __logf(s);
    }
    // agent-scope write-through: visible cross-XCD once drained
    int base = (grp*HW_ + pix0) >> 1;
    AG_ST(&g_lp2[base],     pack2(lpv[0], lpv[1]));
    AG_ST(&g_lp2[base + 1], pack2(lpv[2], lpv[3]));
    // exactly one group owns each pixel's target channel
    #pragma unroll
    for (int k = 0; k < PPT_; ++k)
      if (tcs[k] >= c0 && tcs[k] < c1) AG_ST(&g_vt[pix0 + k], vts[k]);
  }

  // ---- per-tile ticket: last of the 8 group-blocks combines ----
  // __syncthreads drains vmcnt(0) per wave -> all agent stores are at the
  // coherence point before the ticket increments.
  __syncthreads();
  if (tid == 0)
    s_tick = __hip_atomic_fetch_add(&g_tdone[blockIdx.x], 1u,
                                    __ATOMIC_RELAXED, __HIP_MEMORY_SCOPE_AGENT);
  __syncthreads();
  if ((s_tick & (unsigned)(G_-1)) != (unsigned)(G_-1)) return;

  // winner: combine all 8 groups' LSE partials for this tile
  float nll = 0.0f, cnt = 0.0f;
  if (act) {
    float m2[PPT_], s2[PPT_];
    {
      u64 a = AG_LD(&g_lp2[pix0 >> 1]);
      u64 b = AG_LD(&g_lp2[(pix0 >> 1) + 1]);
      unpack2(a, m2[0], m2[1]); unpack2(b, m2[2], m2[3]);
      #pragma unroll
      for (int k = 0; k < PPT_; ++k) s2[k] = 1.0f;
    }
    #pragma unroll
    for (int g = 1; g < G_; ++g) {
      int base = (g*HW_ + pix0) >> 1;
      u64 a = AG_LD(&g_lp2[base]);
      u64 b = AG_LD(&g_lp2[base + 1]);
      float lg[PPT_];
      unpack2(a, lg[0], lg[1]); unpack2(b, lg[2], lg[3]);
      #pragma unroll
      for (int k = 0; k < PPT_; ++k) {
        float d = lg[k] - m2[k];
        float e = __expf(-fabsf(d));
        s2[k] = (d > 0.0f) ? fmaf(s2[k], e, 1.0f) : (s2[k] + e);
        m2[k] = fmaxf(m2[k], lg[k]);
      }
    }
    #pragma unroll
    for (int k = 0; k < PPT_; ++k) {
      float vt = AG_LD(&g_vt[pix0 + k]);
      bool valid = (graw[k] != IGN_);
      nll += valid ? (m2[k] + __logf(s2[k]) - vt) : 0.0f;
      cnt += valid ? 1.0f : 0.0f;
    }
  }

  for (int off = 32; off >= 1; off >>= 1) {
    nll += __shfl_down(nll, off, 64);
    cnt += __shfl_down(cnt, off, 64);
  }
  int lane = tid & 63, wid = tid >> 6;
  if (lane == 0) { red[wid*2] = nll; red[wid*2+1] = cnt; }
  __syncthreads();
  if (tid == 0) {
    float ts  = red[0] + red[2] + red[4] + red[6];
    float tcn = red[1] + red[3] + red[5] + red[7];
    AG_ST(&g_part[blockIdx.x*2],     ts);
    AG_ST(&g_part[blockIdx.x*2 + 1], tcn);
    // same-thread order: partial stores must COMPLETE before the ticket
    asm volatile("s_waitcnt vmcnt(0)" ::: "memory");
    unsigned d = __hip_atomic_fetch_add(&g_done, 1u,
                                        __ATOMIC_RELAXED, __HIP_MEMORY_SCOPE_AGENT);
    s_fin = ((d % (unsigned)GX_) == (unsigned)(GX_-1)) ? 1u : 0u;
  }
  __syncthreads();
  if (s_fin) {
    // last tile-winner overall: fold 157 partials, write the loss
    float a = 0.0f, b = 0.0f;
    if (tid < GX_) {
      a = AG_LD(&g_part[tid*2]);
      b = AG_LD(&g_part[tid*2 + 1]);
    }
    for (int off = 32; off >= 1; off >>= 1) {
      a += __shfl_down(a, off, 64);
      b += __shfl_down(b, off, 64);
    }
    if (lane == 0) { red[wid*2] = a; red[wid*2+1] = b; }
    __syncthreads();
    if (tid == 0) {
      float ts  = red[0] + red[2] + red[4] + red[6];
      float tcn = red[1] + red[3] + red[5] + red[7];
      out[NCH_*HW_] = ts / fmaxf(tcn, 1.0f);   // LOSS_W = 1.0
    }
  }
}

extern "C" void kernel_launch(void* const* d_in, const int* in_sizes, int n_in,
                              void* d_out, int out_size, void* d_ws, size_t ws_size,
                              hipStream_t stream) {
  const float* mask_logits = (const float*)d_in[0];
  const float* stuff_logit = (const float*)d_in[1];
  const float* thing_logit = (const float*)d_in[2];
  const float* bbox        = (const float*)d_in[3];
  const int*   cls_idx     = (const int*)d_in[4];
  const int*   gt          = (const int*)d_in[5];
  float* out = (float*)d_out;

  dim3 grid1(GX_, G_);
  main_kernel<<<grid1, BT_, 0, stream>>>(mask_logits, stuff_logit, thing_logit,
                                         bbox, cls_idx, gt, out);
}

// Round 10
// 223.505 us; speedup vs baseline: 1.0124x; 1.0124x over previous
//
#include <hip/hip_runtime.h>
#include <math.h>

#define N_   128
#define H_   400
#define W_   400
#define MS_  28
#define CT_  80
#define CS_  53
#define HW_  (H_*W_)
#define NCH_ (CS_ + N_)   // 181
#define WG_  1600
#define IGN_ 255
#define G_   8            // channel groups (power of 2!)
#define CPG_ 23           // ceil(181/8)
#define PPT_ 4            // pixels per thread (float4)
#define BT_  256          // threads per block
#define PPB_ (BT_*PPT_)   // 1024 pixels per block
#define GX_  ((HW_ + PPB_ - 1)/PPB_)   // 157

typedef float f4 __attribute__((ext_vector_type(4)));
typedef unsigned long long u64;

struct NParam {
  int vy_lo, vy_hi, vx_lo, vx_hi;   // mask-valid box (inclusive)
  int cy1, cy2, cx1, cx2;           // sem box (y in [cy1,cy2), x in [cx1,cx2))
  float sy, sx;                     // 28/hh, 28/ww
  int y0b, x0b;                     // floor(bbox/4)
  int mlbase, thbase;               // offsets into mask_logits / thing_logit
  int pad0, pad1;                   // 64 B
};

// Device globals. Tickets are EPOCH counters (monotonic, old%G picks the
// winner) -> no zeroing needed, graph-replay and rocprof-replay safe.
// g_lp2/g_vt/g_part are fully rewritten each launch before being read, and
// all cross-block traffic uses agent-scope (cache-bypassing) accesses ->
// no reliance on cross-XCD L2 coherence.
__device__ unsigned int g_tdone[GX_];     // per-tile ticket
__device__ unsigned int g_done;           // global ticket
__device__ u64          g_lp2[(G_*HW_)/2];// per-(group,pixel) LSE m+log(s), packed 2xf32
__device__ float        g_vt[HW_];        // target-channel logit per pixel
__device__ float        g_part[GX_*2];    // per-tile (nll,cnt) partials

static __device__ __forceinline__ u64 pack2(float a, float b) {
  union { float f[2]; u64 u; } t; t.f[0] = a; t.f[1] = b; return t.u;
}
static __device__ __forceinline__ void unpack2(u64 u, float& a, float& b) {
  union { float f[2]; u64 u; } t; t.u = u; a = t.f[0]; b = t.f[1];
}
#define AG_ST(p, v) __hip_atomic_store((p), (v), __ATOMIC_RELAXED, __HIP_MEMORY_SCOPE_AGENT)
#define AG_LD(p)    __hip_atomic_load((p), __ATOMIC_RELAXED, __HIP_MEMORY_SCOPE_AGENT)

__device__ __forceinline__ void lse_update(float v, float& m, float& s) {
  float d = v - m;
  float e = __expf(-fabsf(d));
  s = (d > 0.0f) ? fmaf(s, e, 1.0f) : (s + e);
  m = fmaxf(m, v);
}

// Fused: blockIdx.x = pixel tile (4 px/thread), blockIdx.y = channel group.
// Stuff channels run in two phases:
//   A) pure streaming copy (no use of loaded value -> compiler pipelines it
//      memcpy-style; loads/stores share vmcnt, so ANY consumer wait would
//      drain the store queue -- this phase has none),
//   B) lse + target-capture re-reading stuff_logit (L2-hot, no aliasing).
// Thing channels: (1) wave-uniform active bitmask, (2) scalar-branch
// zero-store burst, (3) ctz-walk of active channels with bilinear compute.
// Last group-block per tile (ticket) combines the 8 partial LSEs and reduces
// NLL; last tile-winner overall (ticket) writes the loss.
__global__ __launch_bounds__(256) void main_kernel(
    const float* __restrict__ mask_logits,
    const float* __restrict__ stuff_logit,
    const float* __restrict__ thing_logit,
    const float* __restrict__ bbox,
    const int*   __restrict__ cls_idx,
    const int*   __restrict__ gt,
    float* __restrict__ out)
{
  __shared__ NParam spar[N_];
  __shared__ int4   sbox[N_];   // superbox = union(sem box, mask box), inclusive
  __shared__ float  red[8];
  __shared__ unsigned s_tick, s_fin;
  int tid = threadIdx.x;
  if (tid < N_) {
    int n = tid;
    float b0 = bbox[4*n+0]*0.25f, b1 = bbox[4*n+1]*0.25f,
          b2 = bbox[4*n+2]*0.25f, b3 = bbox[4*n+3]*0.25f;
    int x0b = (int)floorf(b0), y0b = (int)floorf(b1);
    int x2b = (int)floorf(b2), y2b = (int)floorf(b3);
    int hh = y2b - y0b + 1, ww = x2b - x0b + 1;
    NParam p;
    p.vy_lo = max(y0b, 0); p.vy_hi = min(y2b, H_-1);
    p.vx_lo = max(x0b, 0); p.vx_hi = min(x2b, W_-1);
    p.cy1 = (int)b1; p.cx1 = (int)b0;                 // trunc (positive)
    p.cy2 = (int)(rintf(b3) + 1.0f);                  // jnp.round = RNE
    p.cx2 = (int)(rintf(b2) + 1.0f);
    p.sy = 28.0f / (float)hh; p.sx = 28.0f / (float)ww;
    p.y0b = y0b; p.x0b = x0b;
    int cls = cls_idx[n];
    p.mlbase = (n*CT_ + cls)*(MS_*MS_);
    p.thbase = cls*HW_;
    p.pad0 = 0; p.pad1 = 0;
    spar[n] = p;
    sbox[n] = make_int4(min(p.vy_lo, p.cy1), max(p.vy_hi, p.cy2 - 1),
                        min(p.vx_lo, p.cx1), max(p.vx_hi, p.cx2 - 1));
  }
  __syncthreads();

  int pix0 = (blockIdx.x*BT_ + tid)*PPT_;
  bool act = (pix0 < HW_);
  int grp = blockIdx.y;
  int c0 = grp*CPG_;
  int c1 = min(NCH_, c0 + CPG_);

  int y = 0, xb = 0;
  int graw[PPT_];
  #pragma unroll
  for (int k = 0; k < PPT_; ++k) graw[k] = IGN_;

  if (act) {
    y  = pix0 / W_;              // W_ % 4 == 0: all 4 pixels share y
    xb = pix0 - y*W_;

    // target channel per pixel (gt line is cache-hot across the 8 groups)
    int tcs[PPT_];
    #pragma unroll
    for (int k = 0; k < PPT_; ++k) {
      int g = gt[y*(4*WG_) + (xb + k)*4];
      graw[k] = g;
      tcs[k] = min(max(g, 0), NCH_-1);
    }

    float mv[PPT_], sv[PPT_], vts[PPT_];
    #pragma unroll
    for (int k = 0; k < PPT_; ++k) { mv[k] = -INFINITY; sv[k] = 0.0f; vts[k] = 0.0f; }

    int cs_end = min(c1, CS_);

    // ---- stuff Phase A: PURE streaming copy (memcpy pattern, deep pipe) ----
    for (int c = c0; c < cs_end; ++c) {
      f4 v = *(const f4*)(stuff_logit + c*HW_ + pix0);
      *(f4*)(out + c*HW_ + pix0) = v;
    }

    // ---- stuff Phase B: lse + target capture from L2-hot stuff_logit ----
    {
      int c = c0;
      for (; c + 3 < cs_end; c += 4) {
        f4 v0 = *(const f4*)(stuff_logit + (c+0)*HW_ + pix0);
        f4 v1 = *(const f4*)(stuff_logit + (c+1)*HW_ + pix0);
        f4 v2 = *(const f4*)(stuff_logit + (c+2)*HW_ + pix0);
        f4 v3 = *(const f4*)(stuff_logit + (c+3)*HW_ + pix0);
        #pragma unroll
        for (int k = 0; k < PPT_; ++k) {
          lse_update(v0[k], mv[k], sv[k]);
          lse_update(v1[k], mv[k], sv[k]);
          lse_update(v2[k], mv[k], sv[k]);
          lse_update(v3[k], mv[k], sv[k]);
          if (c+0 == tcs[k]) vts[k] = v0[k];
          if (c+1 == tcs[k]) vts[k] = v1[k];
          if (c+2 == tcs[k]) vts[k] = v2[k];
          if (c+3 == tcs[k]) vts[k] = v3[k];
        }
      }
      for (; c < cs_end; ++c) {
        f4 v = *(const f4*)(stuff_logit + c*HW_ + pix0);
        #pragma unroll
        for (int k = 0; k < PPT_; ++k) {
          lse_update(v[k], mv[k], sv[k]);
          if (c == tcs[k]) vts[k] = v[k];
        }
      }
    }

    // ---- thing channels: 3-pass (mask / zero-burst / active) ----
    int cth0 = max(c0, CS_);
    int nth  = c1 - cth0;              // 0 for pure-stuff groups
    // Pass 1: wave-uniform active bitmask (no memory traffic)
    unsigned amask = 0u;
    for (int i = 0; i < nth; ++i) {
      int4 u = sbox[cth0 - CS_ + i];
      bool rej = (y < u.x) | (y > u.y) | (xb > u.w) | (xb + PPT_ - 1 < u.z);
      if (!__all(rej)) amask |= (1u << i);
    }
    amask = __builtin_amdgcn_readfirstlane(amask);  // SGPR -> scalar branches
    int zc = nth - __popc(amask);      // wave-uniform
    // Pass 2: dense zero-store burst over rejected channels (scalar branch
    // per iter -> stores fire back-to-back, high store ILP, no waits).
    {
      f4 z = {0.0f, 0.0f, 0.0f, 0.0f};
      for (int i = 0; i < nth; ++i) {
        if (!((amask >> i) & 1u))
          *(f4*)(out + (cth0 + i)*HW_ + pix0) = z;
      }
    }
    // Pass 3: active channels only (expected ~1-2 per wave)
    unsigned am = amask;
    while (am) {
      int i = __builtin_ctz(am); am &= am - 1u;
      int cc = cth0 + i;
      int n = cc - CS_;
      NParam p = spar[n];
      float vv[PPT_] = {0.0f, 0.0f, 0.0f, 0.0f};
      if (y >= p.cy1 && y < p.cy2 && xb < p.cx2 && xb+PPT_-1 >= p.cx1) {
        f4 t = *(const f4*)(thing_logit + p.thbase + pix0);
        #pragma unroll
        for (int k = 0; k < PPT_; ++k) {
          int x = xb + k;
          if (x >= p.cx1 && x < p.cx2) vv[k] = t[k];
        }
      }
      if (y >= p.vy_lo && y <= p.vy_hi && xb <= p.vx_hi && xb+PPT_-1 >= p.vx_lo) {
        float srcy = ((float)(y - p.y0b) + 0.5f)*p.sy - 0.5f;
        float fy = floorf(srcy); float ty = srcy - fy;
        int i0 = (int)fminf(fmaxf(fy,        0.0f), (float)(MS_-1));
        int i1 = (int)fminf(fmaxf(fy + 1.0f, 0.0f), (float)(MS_-1));
        const float* r0p = mask_logits + p.mlbase + i0*MS_;
        const float* r1p = mask_logits + p.mlbase + i1*MS_;
        #pragma unroll
        for (int k = 0; k < PPT_; ++k) {
          int x = xb + k;
          if (x >= p.vx_lo && x <= p.vx_hi) {
            float srcx = ((float)(x - p.x0b) + 0.5f)*p.sx - 0.5f;
            float fx = floorf(srcx); float tx = srcx - fx;
            int j0 = (int)fminf(fmaxf(fx,        0.0f), (float)(MS_-1));
            int j1 = (int)fminf(fmaxf(fx + 1.0f, 0.0f), (float)(MS_-1));
            float r0 = r0p[j0]*(1.0f - tx) + r0p[j1]*tx;
            float r1 = r1p[j0]*(1.0f - tx) + r1p[j1]*tx;
            vv[k] += r0*(1.0f - ty) + r1*ty;
          }
        }
      }
      f4 ov = {vv[0], vv[1], vv[2], vv[3]};
      *(f4*)(out + cc*HW_ + pix0) = ov;
      #pragma unroll
      for (int k = 0; k < PPT_; ++k) {
        lse_update(vv[k], mv[k], sv[k]);
        if (cc == tcs[k]) vts[k] = vv[k];
      }
    }

    // merge skipped zero-channels analytically; compress lp = m + log(s)
    float zcf = (float)zc;
    float lpv[PPT_];
    #pragma unroll
    for (int k = 0; k < PPT_; ++k) {
      float m = mv[k], s = sv[k];
      if (zc > 0) {
        if (m >= 0.0f) { s = fmaf(zcf, __expf(-m), s); }
        else           { s = fmaf(s, __expf(m), zcf); m = 0.0f; }  // m=-inf ok: s->zcf
      }
      lpv[k] = m + __logf(s);
    }
    // agent-scope write-through: visible cross-XCD once drained
    int base = (grp*HW_ + pix0) >> 1;
    AG_ST(&g_lp2[base],     pack2(lpv[0], lpv[1]));
    AG_ST(&g_lp2[base + 1], pack2(lpv[2], lpv[3]));
    // exactly one group owns each pixel's target channel
    #pragma unroll
    for (int k = 0; k < PPT_; ++k)
      if (tcs[k] >= c0 && tcs[k] < c1) AG_ST(&g_vt[pix0 + k], vts[k]);
  }

  // ---- per-tile ticket: last of the 8 group-blocks combines ----
  // __syncthreads drains vmcnt(0) per wave -> all agent stores are at the
  // coherence point before the ticket increments.
  __syncthreads();
  if (tid == 0)
    s_tick = __hip_atomic_fetch_add(&g_tdone[blockIdx.x], 1u,
                                    __ATOMIC_RELAXED, __HIP_MEMORY_SCOPE_AGENT);
  __syncthreads();
  if ((s_tick & (unsigned)(G_-1)) != (unsigned)(G_-1)) return;

  // winner: combine all 8 groups' LSE partials for this tile
  float nll = 0.0f, cnt = 0.0f;
  if (act) {
    float m2[PPT_], s2[PPT_];
    {
      u64 a = AG_LD(&g_lp2[pix0 >> 1]);
      u64 b = AG_LD(&g_lp2[(pix0 >> 1) + 1]);
      unpack2(a, m2[0], m2[1]); unpack2(b, m2[2], m2[3]);
      #pragma unroll
      for (int k = 0; k < PPT_; ++k) s2[k] = 1.0f;
    }
    #pragma unroll
    for (int g = 1; g < G_; ++g) {
      int base = (g*HW_ + pix0) >> 1;
      u64 a = AG_LD(&g_lp2[base]);
      u64 b = AG_LD(&g_lp2[base + 1]);
      float lg[PPT_];
      unpack2(a, lg[0], lg[1]); unpack2(b, lg[2], lg[3]);
      #pragma unroll
      for (int k = 0; k < PPT_; ++k) {
        float d = lg[k] - m2[k];
        float e = __expf(-fabsf(d));
        s2[k] = (d > 0.0f) ? fmaf(s2[k], e, 1.0f) : (s2[k] + e);
        m2[k] = fmaxf(m2[k], lg[k]);
      }
    }
    #pragma unroll
    for (int k = 0; k < PPT_; ++k) {
      float vt = AG_LD(&g_vt[pix0 + k]);
      bool valid = (graw[k] != IGN_);
      nll += valid ? (m2[k] + __logf(s2[k]) - vt) : 0.0f;
      cnt += valid ? 1.0f : 0.0f;
    }
  }

  for (int off = 32; off >= 1; off >>= 1) {
    nll += __shfl_down(nll, off, 64);
    cnt += __shfl_down(cnt, off, 64);
  }
  int lane = tid & 63, wid = tid >> 6;
  if (lane == 0) { red[wid*2] = nll; red[wid*2+1] = cnt; }
  __syncthreads();
  if (tid == 0) {
    float ts  = red[0] + red[2] + red[4] + red[6];
    float tcn = red[1] + red[3] + red[5] + red[7];
    AG_ST(&g_part[blockIdx.x*2],     ts);
    AG_ST(&g_part[blockIdx.x*2 + 1], tcn);
    // same-thread order: partial stores must COMPLETE before the ticket
    asm volatile("s_waitcnt vmcnt(0)" ::: "memory");
    unsigned d = __hip_atomic_fetch_add(&g_done, 1u,
                                        __ATOMIC_RELAXED, __HIP_MEMORY_SCOPE_AGENT);
    s_fin = ((d % (unsigned)GX_) == (unsigned)(GX_-1)) ? 1u : 0u;
  }
  __syncthreads();
  if (s_fin) {
    // last tile-winner overall: fold 157 partials, write the loss
    float a = 0.0f, b = 0.0f;
    if (tid < GX_) {
      a = AG_LD(&g_part[tid*2]);
      b = AG_LD(&g_part[tid*2 + 1]);
    }
    for (int off = 32; off >= 1; off >>= 1) {
      a += __shfl_down(a, off, 64);
      b += __shfl_down(b, off, 64);
    }
    if (lane == 0) { red[wid*2] = a; red[wid*2+1] = b; }
    __syncthreads();
    if (tid == 0) {
      float ts  = red[0] + red[2] + red[4] + red[6];
      float tcn = red[1] + red[3] + red[5] + red[7];
      out[NCH_*HW_] = ts / fmaxf(tcn, 1.0f);   // LOSS_W = 1.0
    }
  }
}

extern "C" void kernel_launch(void* const* d_in, const int* in_sizes, int n_in,
                              void* d_out, int out_size, void* d_ws, size_t ws_size,
                              hipStream_t stream) {
  const float* mask_logits = (const float*)d_in[0];
  const float* stuff_logit = (const float*)d_in[1];
  const float* thing_logit = (const float*)d_in[2];
  const float* bbox        = (const float*)d_in[3];
  const int*   cls_idx     = (const int*)d_in[4];
  const int*   gt          = (const int*)d_in[5];
  float* out = (float*)d_out;

  dim3 grid1(GX_, G_);
  main_kernel<<<grid1, BT_, 0, stream>>>(mask_logits, stuff_logit, thing_logit,
                                         bbox, cls_idx, gt, out);
}

// Round 11
// 220.707 us; speedup vs baseline: 1.0253x; 1.0127x over previous
//
#include <hip/hip_runtime.h>
#include <math.h>

#define N_   128
#define H_   400
#define W_   400
#define MS_  28
#define CT_  80
#define CS_  53
#define HW_  (H_*W_)
#define NCH_ (CS_ + N_)   // 181
#define WG_  1600
#define IGN_ 255
#define G_   8            // channel groups (power of 2!)
#define NTH_G 16          // thing channels per group: 128/8 exactly
#define PPT_ 4            // pixels per thread (float4)
#define BT_  256          // threads per block
#define PPB_ (BT_*PPT_)   // 1024 pixels per block
#define GX_  ((HW_ + PPB_ - 1)/PPB_)   // 157

typedef float f4 __attribute__((ext_vector_type(4)));
typedef unsigned long long u64;

struct NParam {
  int vy_lo, vy_hi, vx_lo, vx_hi;   // mask-valid box (inclusive)
  int cy1, cy2, cx1, cx2;           // sem box (y in [cy1,cy2), x in [cx1,cx2))
  float sy, sx;                     // 28/hh, 28/ww
  int y0b, x0b;                     // floor(bbox/4)
  int mlbase, thbase;               // offsets into mask_logits / thing_logit
  int pad0, pad1;                   // 64 B
};

// Device globals. Tickets are EPOCH counters (monotonic, old%G picks the
// winner) -> no zeroing needed, graph-replay and rocprof-replay safe.
// g_lp2/g_vt/g_part are fully rewritten each launch before being read, and
// all cross-block traffic uses agent-scope (cache-bypassing) accesses ->
// no reliance on cross-XCD L2 coherence.
__device__ unsigned int g_tdone[GX_];     // per-tile ticket
__device__ unsigned int g_done;           // global ticket
__device__ u64          g_lp2[(G_*HW_)/2];// per-(group,pixel) LSE m+log(s), packed 2xf32
__device__ float        g_vt[HW_];        // target-channel logit per pixel
__device__ float        g_part[GX_*2];    // per-tile (nll,cnt) partials

static __device__ __forceinline__ u64 pack2(float a, float b) {
  union { float f[2]; u64 u; } t; t.f[0] = a; t.f[1] = b; return t.u;
}
static __device__ __forceinline__ void unpack2(u64 u, float& a, float& b) {
  union { float f[2]; u64 u; } t; t.u = u; a = t.f[0]; b = t.f[1];
}
#define AG_ST(p, v) __hip_atomic_store((p), (v), __ATOMIC_RELAXED, __HIP_MEMORY_SCOPE_AGENT)
#define AG_LD(p)    __hip_atomic_load((p), __ATOMIC_RELAXED, __HIP_MEMORY_SCOPE_AGENT)

__device__ __forceinline__ void lse_update(float v, float& m, float& s) {
  float d = v - m;
  float e = __expf(-fabsf(d));
  s = (d > 0.0f) ? fmaf(s, e, 1.0f) : (s + e);
  m = fmaxf(m, v);
}

// Fused, LOAD-BALANCED: blockIdx.x = pixel tile (4 px/thread),
// blockIdx.y = channel group g owning channels {c : c % 8 == g}
// -> every block gets 6-7 stuff + exactly 16 thing channels (the old
// contiguous split put all 53 stuff channels on 3/8 of the blocks; with
// the whole grid resident from t=0, those blocks WERE the kernel time).
// Thing channels: (1) wave-uniform active bitmask, (2) scalar-branch
// zero-store burst, (3) ctz-walk of active channels with bilinear compute.
// Last group-block per tile (ticket) combines the 8 partial LSEs and reduces
// NLL; last tile-winner overall (ticket) writes the loss.
__global__ __launch_bounds__(256) void main_kernel(
    const float* __restrict__ mask_logits,
    const float* __restrict__ stuff_logit,
    const float* __restrict__ thing_logit,
    const float* __restrict__ bbox,
    const int*   __restrict__ cls_idx,
    const int*   __restrict__ gt,
    float* __restrict__ out)
{
  __shared__ NParam spar[NTH_G];
  __shared__ int4   sbox[NTH_G];  // superbox = union(sem box, mask box), inclusive
  __shared__ float  red[8];
  __shared__ unsigned s_tick, s_fin;
  int tid = threadIdx.x;
  int grp = blockIdx.y;
  // first thing channel of this group: smallest c>=53 with c%8==grp
  int cth_start = CS_ + (((grp - (CS_ & 7)) & 7));
  if (tid < NTH_G) {
    int c = cth_start + 8*tid;
    int n = c - CS_;
    float b0 = bbox[4*n+0]*0.25f, b1 = bbox[4*n+1]*0.25f,
          b2 = bbox[4*n+2]*0.25f, b3 = bbox[4*n+3]*0.25f;
    int x0b = (int)floorf(b0), y0b = (int)floorf(b1);
    int x2b = (int)floorf(b2), y2b = (int)floorf(b3);
    int hh = y2b - y0b + 1, ww = x2b - x0b + 1;
    NParam p;
    p.vy_lo = max(y0b, 0); p.vy_hi = min(y2b, H_-1);
    p.vx_lo = max(x0b, 0); p.vx_hi = min(x2b, W_-1);
    p.cy1 = (int)b1; p.cx1 = (int)b0;                 // trunc (positive)
    p.cy2 = (int)(rintf(b3) + 1.0f);                  // jnp.round = RNE
    p.cx2 = (int)(rintf(b2) + 1.0f);
    p.sy = 28.0f / (float)hh; p.sx = 28.0f / (float)ww;
    p.y0b = y0b; p.x0b = x0b;
    int cls = cls_idx[n];
    p.mlbase = (n*CT_ + cls)*(MS_*MS_);
    p.thbase = cls*HW_;
    p.pad0 = 0; p.pad1 = 0;
    spar[tid] = p;
    sbox[tid] = make_int4(min(p.vy_lo, p.cy1), max(p.vy_hi, p.cy2 - 1),
                          min(p.vx_lo, p.cx1), max(p.vx_hi, p.cx2 - 1));
  }
  __syncthreads();

  int pix0 = (blockIdx.x*BT_ + tid)*PPT_;
  bool act = (pix0 < HW_);

  int y = 0, xb = 0;
  int graw[PPT_];
  #pragma unroll
  for (int k = 0; k < PPT_; ++k) graw[k] = IGN_;

  if (act) {
    y  = pix0 / W_;              // W_ % 4 == 0: all 4 pixels share y
    xb = pix0 - y*W_;

    // target channel per pixel (gt line is cache-hot across the 8 groups)
    int tcs[PPT_];
    #pragma unroll
    for (int k = 0; k < PPT_; ++k) {
      int g = gt[y*(4*WG_) + (xb + k)*4];
      graw[k] = g;
      tcs[k] = min(max(g, 0), NCH_-1);
    }

    float mv[PPT_], sv[PPT_], vts[PPT_];
    #pragma unroll
    for (int k = 0; k < PPT_; ++k) { mv[k] = -INFINITY; sv[k] = 0.0f; vts[k] = 0.0f; }

    // ---- stuff channels of this group: c = grp, grp+8, ... < 53 ----
    for (int c = grp; c < CS_; c += G_) {
      f4 v = *(const f4*)(stuff_logit + c*HW_ + pix0);
      *(f4*)(out + c*HW_ + pix0) = v;
      #pragma unroll
      for (int k = 0; k < PPT_; ++k) {
        lse_update(v[k], mv[k], sv[k]);
        if (c == tcs[k]) vts[k] = v[k];
      }
    }

    // ---- thing channels: 3-pass (mask / zero-burst / active) ----
    // Pass 1: wave-uniform active bitmask (no memory traffic)
    unsigned amask = 0u;
    #pragma unroll
    for (int i = 0; i < NTH_G; ++i) {
      int4 u = sbox[i];
      bool rej = (y < u.x) | (y > u.y) | (xb > u.w) | (xb + PPT_ - 1 < u.z);
      if (!__all(rej)) amask |= (1u << i);
    }
    amask = __builtin_amdgcn_readfirstlane(amask);  // SGPR -> scalar branches
    int zc = NTH_G - __popc(amask);    // wave-uniform
    // Pass 2: dense zero-store burst over rejected channels (scalar branch
    // per iter -> stores fire back-to-back, high store ILP, no waits).
    {
      f4 z = {0.0f, 0.0f, 0.0f, 0.0f};
      for (int i = 0; i < NTH_G; ++i) {
        if (!((amask >> i) & 1u))
          *(f4*)(out + (cth_start + 8*i)*HW_ + pix0) = z;
      }
    }
    // Pass 3: active channels only (expected ~1-2 per wave)
    unsigned am = amask;
    while (am) {
      int i = __builtin_ctz(am); am &= am - 1u;
      int cc = cth_start + 8*i;
      NParam p = spar[i];
      float vv[PPT_] = {0.0f, 0.0f, 0.0f, 0.0f};
      if (y >= p.cy1 && y < p.cy2 && xb < p.cx2 && xb+PPT_-1 >= p.cx1) {
        f4 t = *(const f4*)(thing_logit + p.thbase + pix0);
        #pragma unroll
        for (int k = 0; k < PPT_; ++k) {
          int x = xb + k;
          if (x >= p.cx1 && x < p.cx2) vv[k] = t[k];
        }
      }
      if (y >= p.vy_lo && y <= p.vy_hi && xb <= p.vx_hi && xb+PPT_-1 >= p.vx_lo) {
        float srcy = ((float)(y - p.y0b) + 0.5f)*p.sy - 0.5f;
        float fy = floorf(srcy); float ty = srcy - fy;
        int i0 = (int)fminf(fmaxf(fy,        0.0f), (float)(MS_-1));
        int i1 = (int)fminf(fmaxf(fy + 1.0f, 0.0f), (float)(MS_-1));
        const float* r0p = mask_logits + p.mlbase + i0*MS_;
        const float* r1p = mask_logits + p.mlbase + i1*MS_;
        #pragma unroll
        for (int k = 0; k < PPT_; ++k) {
          int x = xb + k;
          if (x >= p.vx_lo && x <= p.vx_hi) {
            float srcx = ((float)(x - p.x0b) + 0.5f)*p.sx - 0.5f;
            float fx = floorf(srcx); float tx = srcx - fx;
            int j0 = (int)fminf(fmaxf(fx,        0.0f), (float)(MS_-1));
            int j1 = (int)fminf(fmaxf(fx + 1.0f, 0.0f), (float)(MS_-1));
            float r0 = r0p[j0]*(1.0f - tx) + r0p[j1]*tx;
            float r1 = r1p[j0]*(1.0f - tx) + r1p[j1]*tx;
            vv[k] += r0*(1.0f - ty) + r1*ty;
          }
        }
      }
      f4 ov = {vv[0], vv[1], vv[2], vv[3]};
      *(f4*)(out + cc*HW_ + pix0) = ov;
      #pragma unroll
      for (int k = 0; k < PPT_; ++k) {
        lse_update(vv[k], mv[k], sv[k]);
        if (cc == tcs[k]) vts[k] = vv[k];
      }
    }

    // merge skipped zero-channels analytically; compress lp = m + log(s)
    float zcf = (float)zc;
    float lpv[PPT_];
    #pragma unroll
    for (int k = 0; k < PPT_; ++k) {
      float m = mv[k], s = sv[k];
      if (zc > 0) {
        if (m >= 0.0f) { s = fmaf(zcf, __expf(-m), s); }
        else           { s = fmaf(s, __expf(m), zcf); m = 0.0f; }  // m=-inf ok: s->zcf
      }
      lpv[k] = m + __logf(s);
    }
    // agent-scope write-through: visible cross-XCD once drained
    int base = (grp*HW_ + pix0) >> 1;
    AG_ST(&g_lp2[base],     pack2(lpv[0], lpv[1]));
    AG_ST(&g_lp2[base + 1], pack2(lpv[2], lpv[3]));
    // exactly one group owns each pixel's target channel (tcs % 8 == grp)
    #pragma unroll
    for (int k = 0; k < PPT_; ++k)
      if ((tcs[k] & (G_-1)) == grp) AG_ST(&g_vt[pix0 + k], vts[k]);
  }

  // ---- per-tile ticket: last of the 8 group-blocks combines ----
  // __syncthreads drains vmcnt(0) per wave -> all agent stores are at the
  // coherence point before the ticket increments.
  __syncthreads();
  if (tid == 0)
    s_tick = __hip_atomic_fetch_add(&g_tdone[blockIdx.x], 1u,
                                    __ATOMIC_RELAXED, __HIP_MEMORY_SCOPE_AGENT);
  __syncthreads();
  if ((s_tick & (unsigned)(G_-1)) != (unsigned)(G_-1)) return;

  // winner: combine all 8 groups' LSE partials for this tile
  float nll = 0.0f, cnt = 0.0f;
  if (act) {
    float m2[PPT_], s2[PPT_];
    {
      u64 a = AG_LD(&g_lp2[pix0 >> 1]);
      u64 b = AG_LD(&g_lp2[(pix0 >> 1) + 1]);
      unpack2(a, m2[0], m2[1]); unpack2(b, m2[2], m2[3]);
      #pragma unroll
      for (int k = 0; k < PPT_; ++k) s2[k] = 1.0f;
    }
    #pragma unroll
    for (int g = 1; g < G_; ++g) {
      int base = (g*HW_ + pix0) >> 1;
      u64 a = AG_LD(&g_lp2[base]);
      u64 b = AG_LD(&g_lp2[base + 1]);
      float lg[PPT_];
      unpack2(a, lg[0], lg[1]); unpack2(b, lg[2], lg[3]);
      #pragma unroll
      for (int k = 0; k < PPT_; ++k) {
        float d = lg[k] - m2[k];
        float e = __expf(-fabsf(d));
        s2[k] = (d > 0.0f) ? fmaf(s2[k], e, 1.0f) : (s2[k] + e);
        m2[k] = fmaxf(m2[k], lg[k]);
      }
    }
    #pragma unroll
    for (int k = 0; k < PPT_; ++k) {
      float vt = AG_LD(&g_vt[pix0 + k]);
      bool valid = (graw[k] != IGN_);
      nll += valid ? (m2[k] + __logf(s2[k]) - vt) : 0.0f;
      cnt += valid ? 1.0f : 0.0f;
    }
  }

  for (int off = 32; off >= 1; off >>= 1) {
    nll += __shfl_down(nll, off, 64);
    cnt += __shfl_down(cnt, off, 64);
  }
  int lane = tid & 63, wid = tid >> 6;
  if (lane == 0) { red[wid*2] = nll; red[wid*2+1] = cnt; }
  __syncthreads();
  if (tid == 0) {
    float ts  = red[0] + red[2] + red[4] + red[6];
    float tcn = red[1] + red[3] + red[5] + red[7];
    AG_ST(&g_part[blockIdx.x*2],     ts);
    AG_ST(&g_part[blockIdx.x*2 + 1], tcn);
    // same-thread order: partial stores must COMPLETE before the ticket
    asm volatile("s_waitcnt vmcnt(0)" ::: "memory");
    unsigned d = __hip_atomic_fetch_add(&g_done, 1u,
                                        __ATOMIC_RELAXED, __HIP_MEMORY_SCOPE_AGENT);
    s_fin = ((d % (unsigned)GX_) == (unsigned)(GX_-1)) ? 1u : 0u;
  }
  __syncthreads();
  if (s_fin) {
    // last tile-winner overall: fold 157 partials, write the loss
    float a = 0.0f, b = 0.0f;
    if (tid < GX_) {
      a = AG_LD(&g_part[tid*2]);
      b = AG_LD(&g_part[tid*2 + 1]);
    }
    for (int off = 32; off >= 1; off >>= 1) {
      a += __shfl_down(a, off, 64);
      b += __shfl_down(b, off, 64);
    }
    if (lane == 0) { red[wid*2] = a; red[wid*2+1] = b; }
    __syncthreads();
    if (tid == 0) {
      float ts  = red[0] + red[2] + red[4] + red[6];
      float tcn = red[1] + red[3] + red[5] + red[7];
      out[NCH_*HW_] = ts / fmaxf(tcn, 1.0f);   // LOSS_W = 1.0
    }
  }
}

extern "C" void kernel_launch(void* const* d_in, const int* in_sizes, int n_in,
                              void* d_out, int out_size, void* d_ws, size_t ws_size,
                              hipStream_t stream) {
  const float* mask_logits = (const float*)d_in[0];
  const float* stuff_logit = (const float*)d_in[1];
  const float* thing_logit = (const float*)d_in[2];
  const float* bbox        = (const float*)d_in[3];
  const int*   cls_idx     = (const int*)d_in[4];
  const int*   gt          = (const int*)d_in[5];
  float* out = (float*)d_out;

  dim3 grid1(GX_, G_);
  main_kernel<<<grid1, BT_, 0, stream>>>(mask_logits, stuff_logit, thing_logit,
                                         bbox, cls_idx, gt, out);
}

// Round 12
// 215.053 us; speedup vs baseline: 1.0522x; 1.0263x over previous
//
#include <hip/hip_runtime.h>
#include <math.h>

#define N_   128
#define H_   400
#define W_   400
#define MS_  28
#define CT_  80
#define CS_  53
#define HW_  (H_*W_)
#define NCH_ (CS_ + N_)   // 181
#define WG_  1600
#define IGN_ 255
#define G_   8            // channel groups (power of 2!)
#define NTH_G 16          // thing channels per group: 128/8 exactly
#define PPT_ 2            // pixels per thread (float2) -> 2504 blocks, ~31 waves/CU
#define BT_  256          // threads per block
#define PPB_ (BT_*PPT_)   // 512 pixels per block
#define GX_  ((HW_ + PPB_ - 1)/PPB_)   // 313

typedef float f2 __attribute__((ext_vector_type(2)));
typedef unsigned long long u64;

#define NT_LD(p)    __builtin_nontemporal_load(p)
#define NT_ST(v, p) __builtin_nontemporal_store((v), (p))

struct NParam {
  int vy_lo, vy_hi, vx_lo, vx_hi;   // mask-valid box (inclusive)
  int cy1, cy2, cx1, cx2;           // sem box (y in [cy1,cy2), x in [cx1,cx2))
  float sy, sx;                     // 28/hh, 28/ww
  int y0b, x0b;                     // floor(bbox/4)
  int mlbase, thbase;               // offsets into mask_logits / thing_logit
  int pad0, pad1;                   // 64 B
};

// Device globals. Tickets are EPOCH counters (monotonic, old%G picks the
// winner) -> no zeroing needed, graph-replay and rocprof-replay safe.
// g_lp2/g_vt/g_part are fully rewritten each launch before being read, and
// all cross-block traffic uses agent-scope (cache-bypassing) accesses ->
// no reliance on cross-XCD L2 coherence.
__device__ unsigned int g_tdone[GX_];     // per-tile ticket
__device__ unsigned int g_done;           // global ticket
__device__ u64          g_lp2[(G_*HW_)/2];// per-(group,pixel-pair) LSE m+log(s), packed 2xf32
__device__ float        g_vt[HW_];        // target-channel logit per pixel
__device__ float        g_part[GX_*2];    // per-tile (nll,cnt) partials

static __device__ __forceinline__ u64 pack2(float a, float b) {
  union { float f[2]; u64 u; } t; t.f[0] = a; t.f[1] = b; return t.u;
}
static __device__ __forceinline__ void unpack2(u64 u, float& a, float& b) {
  union { float f[2]; u64 u; } t; t.u = u; a = t.f[0]; b = t.f[1];
}
#define AG_ST(p, v) __hip_atomic_store((p), (v), __ATOMIC_RELAXED, __HIP_MEMORY_SCOPE_AGENT)
#define AG_LD(p)    __hip_atomic_load((p), __ATOMIC_RELAXED, __HIP_MEMORY_SCOPE_AGENT)

__device__ __forceinline__ void lse_update(float v, float& m, float& s) {
  float d = v - m;
  float e = __expf(-fabsf(d));
  s = (d > 0.0f) ? fmaf(s, e, 1.0f) : (s + e);
  m = fmaxf(m, v);
}

// Fused, balanced (c%8==grp), latency-focused: PPT=2 for ~31 waves/CU of
// outstanding-load concurrency; rolling 1-deep prefetch in the stuff loop;
// nontemporal on single-use streams. Thing channels: bitmask / zero-burst /
// ctz-walk. Per-tile epoch ticket -> winner combines 8 partial LSEs; global
// epoch ticket -> loss.
__global__ __launch_bounds__(256) void main_kernel(
    const float* __restrict__ mask_logits,
    const float* __restrict__ stuff_logit,
    const float* __restrict__ thing_logit,
    const float* __restrict__ bbox,
    const int*   __restrict__ cls_idx,
    const int*   __restrict__ gt,
    float* __restrict__ out)
{
  __shared__ NParam spar[NTH_G];
  __shared__ int4   sbox[NTH_G];  // superbox = union(sem box, mask box), inclusive
  __shared__ float  red[8];
  __shared__ unsigned s_tick, s_fin;
  int tid = threadIdx.x;
  int grp = blockIdx.y;
  // first thing channel of this group: smallest c>=53 with c%8==grp
  int cth_start = CS_ + (((grp - (CS_ & 7)) & 7));
  if (tid < NTH_G) {
    int c = cth_start + 8*tid;
    int n = c - CS_;
    float b0 = bbox[4*n+0]*0.25f, b1 = bbox[4*n+1]*0.25f,
          b2 = bbox[4*n+2]*0.25f, b3 = bbox[4*n+3]*0.25f;
    int x0b = (int)floorf(b0), y0b = (int)floorf(b1);
    int x2b = (int)floorf(b2), y2b = (int)floorf(b3);
    int hh = y2b - y0b + 1, ww = x2b - x0b + 1;
    NParam p;
    p.vy_lo = max(y0b, 0); p.vy_hi = min(y2b, H_-1);
    p.vx_lo = max(x0b, 0); p.vx_hi = min(x2b, W_-1);
    p.cy1 = (int)b1; p.cx1 = (int)b0;                 // trunc (positive)
    p.cy2 = (int)(rintf(b3) + 1.0f);                  // jnp.round = RNE
    p.cx2 = (int)(rintf(b2) + 1.0f);
    p.sy = 28.0f / (float)hh; p.sx = 28.0f / (float)ww;
    p.y0b = y0b; p.x0b = x0b;
    int cls = cls_idx[n];
    p.mlbase = (n*CT_ + cls)*(MS_*MS_);
    p.thbase = cls*HW_;
    p.pad0 = 0; p.pad1 = 0;
    spar[tid] = p;
    sbox[tid] = make_int4(min(p.vy_lo, p.cy1), max(p.vy_hi, p.cy2 - 1),
                          min(p.vx_lo, p.cx1), max(p.vx_hi, p.cx2 - 1));
  }
  __syncthreads();

  int pix0 = (blockIdx.x*BT_ + tid)*PPT_;
  bool act = (pix0 < HW_);

  int y = 0, xb = 0;
  int graw[PPT_];
  #pragma unroll
  for (int k = 0; k < PPT_; ++k) graw[k] = IGN_;

  if (act) {
    y  = pix0 / W_;              // W_ % 2 == 0: both pixels share y
    xb = pix0 - y*W_;

    // target channel per pixel (gt line reused across the 8 groups -> cached)
    int tcs[PPT_];
    #pragma unroll
    for (int k = 0; k < PPT_; ++k) {
      int g = gt[y*(4*WG_) + (xb + k)*4];
      graw[k] = g;
      tcs[k] = min(max(g, 0), NCH_-1);
    }

    float mv[PPT_], sv[PPT_], vts[PPT_];
    #pragma unroll
    for (int k = 0; k < PPT_; ++k) { mv[k] = -INFINITY; sv[k] = 0.0f; vts[k] = 0.0f; }

    // ---- stuff channels of this group (c = grp, grp+8, ... < 53) ----
    // rolling 1-deep prefetch: next channel's load stays in flight while the
    // current one is consumed (lse forces a wait; without this the wait
    // leaves ZERO loads outstanding -> latency exposed every iteration).
    {
      int c = grp;
      if (c < CS_) {
        f2 v = NT_LD((const f2*)(stuff_logit + c*HW_ + pix0));
        for (;;) {
          int cn = c + G_;
          bool more = (cn < CS_);
          f2 vn;
          if (more) vn = NT_LD((const f2*)(stuff_logit + cn*HW_ + pix0));
          NT_ST(v, (f2*)(out + c*HW_ + pix0));
          #pragma unroll
          for (int k = 0; k < PPT_; ++k) {
            lse_update(v[k], mv[k], sv[k]);
            if (c == tcs[k]) vts[k] = v[k];
          }
          if (!more) break;
          v = vn; c = cn;
        }
      }
    }

    // ---- thing channels: 3-pass (mask / zero-burst / active) ----
    // Pass 1: wave-uniform active bitmask (no memory traffic)
    unsigned amask = 0u;
    #pragma unroll
    for (int i = 0; i < NTH_G; ++i) {
      int4 u = sbox[i];
      bool rej = (y < u.x) | (y > u.y) | (xb > u.w) | (xb + PPT_ - 1 < u.z);
      if (!__all(rej)) amask |= (1u << i);
    }
    amask = __builtin_amdgcn_readfirstlane(amask);  // SGPR -> scalar branches
    int zc = NTH_G - __popc(amask);    // wave-uniform
    // Pass 2: dense zero-store burst over rejected channels (scalar branch
    // per iter -> stores fire back-to-back, no waits).
    {
      f2 z = {0.0f, 0.0f};
      for (int i = 0; i < NTH_G; ++i) {
        if (!((amask >> i) & 1u))
          NT_ST(z, (f2*)(out + (cth_start + 8*i)*HW_ + pix0));
      }
    }
    // Pass 3: active channels only (expected ~1-2 per wave)
    unsigned am = amask;
    while (am) {
      int i = __builtin_ctz(am); am &= am - 1u;
      int cc = cth_start + 8*i;
      NParam p = spar[i];
      float vv[PPT_] = {0.0f, 0.0f};
      if (y >= p.cy1 && y < p.cy2 && xb < p.cx2 && xb+PPT_-1 >= p.cx1) {
        f2 t = NT_LD((const f2*)(thing_logit + p.thbase + pix0));
        #pragma unroll
        for (int k = 0; k < PPT_; ++k) {
          int x = xb + k;
          if (x >= p.cx1 && x < p.cx2) vv[k] = t[k];
        }
      }
      if (y >= p.vy_lo && y <= p.vy_hi && xb <= p.vx_hi && xb+PPT_-1 >= p.vx_lo) {
        float srcy = ((float)(y - p.y0b) + 0.5f)*p.sy - 0.5f;
        float fy = floorf(srcy); float ty = srcy - fy;
        int i0 = (int)fminf(fmaxf(fy,        0.0f), (float)(MS_-1));
        int i1 = (int)fminf(fmaxf(fy + 1.0f, 0.0f), (float)(MS_-1));
        const float* r0p = mask_logits + p.mlbase + i0*MS_;
        const float* r1p = mask_logits + p.mlbase + i1*MS_;
        #pragma unroll
        for (int k = 0; k < PPT_; ++k) {
          int x = xb + k;
          if (x >= p.vx_lo && x <= p.vx_hi) {
            float srcx = ((float)(x - p.x0b) + 0.5f)*p.sx - 0.5f;
            float fx = floorf(srcx); float tx = srcx - fx;
            int j0 = (int)fminf(fmaxf(fx,        0.0f), (float)(MS_-1));
            int j1 = (int)fminf(fmaxf(fx + 1.0f, 0.0f), (float)(MS_-1));
            float r0 = r0p[j0]*(1.0f - tx) + r0p[j1]*tx;
            float r1 = r1p[j0]*(1.0f - tx) + r1p[j1]*tx;
            vv[k] += r0*(1.0f - ty) + r1*ty;
          }
        }
      }
      f2 ov = {vv[0], vv[1]};
      NT_ST(ov, (f2*)(out + cc*HW_ + pix0));
      #pragma unroll
      for (int k = 0; k < PPT_; ++k) {
        lse_update(vv[k], mv[k], sv[k]);
        if (cc == tcs[k]) vts[k] = vv[k];
      }
    }

    // merge skipped zero-channels analytically; compress lp = m + log(s)
    float zcf = (float)zc;
    float lpv[PPT_];
    #pragma unroll
    for (int k = 0; k < PPT_; ++k) {
      float m = mv[k], s = sv[k];
      if (zc > 0) {
        if (m >= 0.0f) { s = fmaf(zcf, __expf(-m), s); }
        else           { s = fmaf(s, __expf(m), zcf); m = 0.0f; }  // m=-inf ok: s->zcf
      }
      lpv[k] = m + __logf(s);
    }
    // agent-scope write-through: visible cross-XCD once drained
    AG_ST(&g_lp2[(grp*HW_ + pix0) >> 1], pack2(lpv[0], lpv[1]));
    // exactly one group owns each pixel's target channel (tcs % 8 == grp)
    #pragma unroll
    for (int k = 0; k < PPT_; ++k)
      if ((tcs[k] & (G_-1)) == grp) AG_ST(&g_vt[pix0 + k], vts[k]);
  }

  // ---- per-tile ticket: last of the 8 group-blocks combines ----
  // __syncthreads drains vmcnt(0) per wave -> all agent stores are at the
  // coherence point before the ticket increments.
  __syncthreads();
  if (tid == 0)
    s_tick = __hip_atomic_fetch_add(&g_tdone[blockIdx.x], 1u,
                                    __ATOMIC_RELAXED, __HIP_MEMORY_SCOPE_AGENT);
  __syncthreads();
  if ((s_tick & (unsigned)(G_-1)) != (unsigned)(G_-1)) return;

  // winner: combine all 8 groups' LSE partials for this tile
  float nll = 0.0f, cnt = 0.0f;
  if (act) {
    float m2[PPT_], s2[PPT_];
    {
      u64 a = AG_LD(&g_lp2[pix0 >> 1]);
      unpack2(a, m2[0], m2[1]);
      #pragma unroll
      for (int k = 0; k < PPT_; ++k) s2[k] = 1.0f;
    }
    #pragma unroll
    for (int g = 1; g < G_; ++g) {
      u64 a = AG_LD(&g_lp2[(g*HW_ + pix0) >> 1]);
      float lg[PPT_];
      unpack2(a, lg[0], lg[1]);
      #pragma unroll
      for (int k = 0; k < PPT_; ++k) {
        float d = lg[k] - m2[k];
        float e = __expf(-fabsf(d));
        s2[k] = (d > 0.0f) ? fmaf(s2[k], e, 1.0f) : (s2[k] + e);
        m2[k] = fmaxf(m2[k], lg[k]);
      }
    }
    #pragma unroll
    for (int k = 0; k < PPT_; ++k) {
      float vt = AG_LD(&g_vt[pix0 + k]);
      bool valid = (graw[k] != IGN_);
      nll += valid ? (m2[k] + __logf(s2[k]) - vt) : 0.0f;
      cnt += valid ? 1.0f : 0.0f;
    }
  }

  for (int off = 32; off >= 1; off >>= 1) {
    nll += __shfl_down(nll, off, 64);
    cnt += __shfl_down(cnt, off, 64);
  }
  int lane = tid & 63, wid = tid >> 6;
  if (lane == 0) { red[wid*2] = nll; red[wid*2+1] = cnt; }
  __syncthreads();
  if (tid == 0) {
    float ts  = red[0] + red[2] + red[4] + red[6];
    float tcn = red[1] + red[3] + red[5] + red[7];
    AG_ST(&g_part[blockIdx.x*2],     ts);
    AG_ST(&g_part[blockIdx.x*2 + 1], tcn);
    // same-thread order: partial stores must COMPLETE before the ticket
    asm volatile("s_waitcnt vmcnt(0)" ::: "memory");
    unsigned d = __hip_atomic_fetch_add(&g_done, 1u,
                                        __ATOMIC_RELAXED, __HIP_MEMORY_SCOPE_AGENT);
    s_fin = ((d % (unsigned)GX_) == (unsigned)(GX_-1)) ? 1u : 0u;
  }
  __syncthreads();
  if (s_fin) {
    // last tile-winner overall: fold GX_=313 partials, write the loss
    float a = 0.0f, b = 0.0f;
    if (tid < GX_)       { a += AG_LD(&g_part[tid*2]);       b += AG_LD(&g_part[tid*2 + 1]); }
    if (tid + BT_ < GX_) { a += AG_LD(&g_part[(tid+BT_)*2]); b += AG_LD(&g_part[(tid+BT_)*2 + 1]); }
    for (int off = 32; off >= 1; off >>= 1) {
      a += __shfl_down(a, off, 64);
      b += __shfl_down(b, off, 64);
    }
    if (lane == 0) { red[wid*2] = a; red[wid*2+1] = b; }
    __syncthreads();
    if (tid == 0) {
      float ts  = red[0] + red[2] + red[4] + red[6];
      float tcn = red[1] + red[3] + red[5] + red[7];
      out[NCH_*HW_] = ts / fmaxf(tcn, 1.0f);   // LOSS_W = 1.0
    }
  }
}

extern "C" void kernel_launch(void* const* d_in, const int* in_sizes, int n_in,
                              void* d_out, int out_size, void* d_ws, size_t ws_size,
                              hipStream_t stream) {
  const float* mask_logits = (const float*)d_in[0];
  const float* stuff_logit = (const float*)d_in[1];
  const float* thing_logit = (const float*)d_in[2];
  const float* bbox        = (const float*)d_in[3];
  const int*   cls_idx     = (const int*)d_in[4];
  const int*   gt          = (const int*)d_in[5];
  float* out = (float*)d_out;

  dim3 grid1(GX_, G_);
  main_kernel<<<grid1, BT_, 0, stream>>>(mask_logits, stuff_logit, thing_logit,
                                         bbox, cls_idx, gt, out);
}

// Round 13
// 213.998 us; speedup vs baseline: 1.0574x; 1.0049x over previous
//
#include <hip/hip_runtime.h>
#include <math.h>

#define N_   128
#define H_   400
#define W_   400
#define MS_  28
#define CT_  80
#define CS_  53
#define HW_  (H_*W_)
#define NCH_ (CS_ + N_)   // 181
#define WG_  1600
#define IGN_ 255
#define G_   8            // channel groups == waves per block
#define NTH_G 16          // thing channels per group: 128/8 exactly
#define PPT_ 2            // pixels per thread (float2)
#define BT_  512          // 8 waves per block; wave w = channel group w
#define TPX_ 128          // pixels per block (64 lanes * PPT)
#define GX_  (HW_/TPX_)   // 1250 blocks (exact)

typedef float f2 __attribute__((ext_vector_type(2)));

#define NT_LD(p)    __builtin_nontemporal_load(p)
#define NT_ST(v, p) __builtin_nontemporal_store((v), (p))

struct NParam {
  int vy_lo, vy_hi, vx_lo, vx_hi;   // mask-valid box (inclusive)
  int cy1, cy2, cx1, cx2;           // sem box (y in [cy1,cy2), x in [cx1,cx2))
  float sy, sx;                     // 28/hh, 28/ww
  int y0b, x0b;                     // floor(bbox/4)
  int mlbase, thbase;               // offsets into mask_logits / thing_logit
  int pad0, pad1;                   // 64 B
};

// Device globals. g_done is an EPOCH counter (monotonic, old%GX picks the
// winner) -> no zeroing needed, graph-replay and rocprof-replay safe.
// g_part is fully rewritten each launch before being read; cross-block
// traffic uses agent-scope (cache-bypassing) accesses -> no reliance on
// cross-XCD L2 coherence.
__device__ unsigned int g_done;           // global ticket
__device__ float        g_part[GX_*2];    // per-block (nll,cnt) partials

#define AG_ST(p, v) __hip_atomic_store((p), (v), __ATOMIC_RELAXED, __HIP_MEMORY_SCOPE_AGENT)
#define AG_LD(p)    __hip_atomic_load((p), __ATOMIC_RELAXED, __HIP_MEMORY_SCOPE_AGENT)

__device__ __forceinline__ void lse_update(float v, float& m, float& s) {
  float d = v - m;
  float e = __expf(-fabsf(d));
  s = (d > 0.0f) ? fmaf(s, e, 1.0f) : (s + e);
  m = fmaxf(m, v);
}

// Fused, single-block-per-tile: 8 waves = 8 channel groups (c % 8 == w),
// all covering the SAME 128 pixels. LSE combine is an intra-block LDS
// exchange -- no global lp round-trip, no per-tile tickets. Per-wave:
// rolling-prefetch NT stuff copy+lse; thing channels via wave-uniform
// bitmask / zero-store burst / ctz-walk. One global epoch ticket for loss.
__global__ __launch_bounds__(512) void main_kernel(
    const float* __restrict__ mask_logits,
    const float* __restrict__ stuff_logit,
    const float* __restrict__ thing_logit,
    const float* __restrict__ bbox,
    const int*   __restrict__ cls_idx,
    const int*   __restrict__ gt,
    float* __restrict__ out)
{
  __shared__ NParam spar[N_];
  __shared__ int4   sbox[N_];       // superbox = union(sem, mask), inclusive
  __shared__ float  lp_lds[G_][TPX_];
  __shared__ float  vt_lds[TPX_];
  __shared__ float  red[16];
  __shared__ unsigned s_fin;
  int tid = threadIdx.x;
  if (tid < N_) {
    int n = tid;
    float b0 = bbox[4*n+0]*0.25f, b1 = bbox[4*n+1]*0.25f,
          b2 = bbox[4*n+2]*0.25f, b3 = bbox[4*n+3]*0.25f;
    int x0b = (int)floorf(b0), y0b = (int)floorf(b1);
    int x2b = (int)floorf(b2), y2b = (int)floorf(b3);
    int hh = y2b - y0b + 1, ww = x2b - x0b + 1;
    NParam p;
    p.vy_lo = max(y0b, 0); p.vy_hi = min(y2b, H_-1);
    p.vx_lo = max(x0b, 0); p.vx_hi = min(x2b, W_-1);
    p.cy1 = (int)b1; p.cx1 = (int)b0;                 // trunc (positive)
    p.cy2 = (int)(rintf(b3) + 1.0f);                  // jnp.round = RNE
    p.cx2 = (int)(rintf(b2) + 1.0f);
    p.sy = 28.0f / (float)hh; p.sx = 28.0f / (float)ww;
    p.y0b = y0b; p.x0b = x0b;
    int cls = cls_idx[n];
    p.mlbase = (n*CT_ + cls)*(MS_*MS_);
    p.thbase = cls*HW_;
    p.pad0 = 0; p.pad1 = 0;
    spar[n] = p;
    sbox[n] = make_int4(min(p.vy_lo, p.cy1), max(p.vy_hi, p.cy2 - 1),
                        min(p.vx_lo, p.cx1), max(p.vx_hi, p.cx2 - 1));
  }
  __syncthreads();

  int grp  = tid >> 6;              // wave id == channel group
  int lane = tid & 63;
  int pix0 = blockIdx.x*TPX_ + lane*PPT_;
  int y  = pix0 / W_;               // W_ even, pix0 even -> pair shares row
  int xb = pix0 - y*W_;
  // first thing channel of this group: smallest c>=53 with c%8==grp
  int cth_start = CS_ + ((grp - (CS_ & 7)) & 7);

  // target channel per pixel
  int tcs[PPT_];
  #pragma unroll
  for (int k = 0; k < PPT_; ++k) {
    int g = gt[y*(4*WG_) + (xb + k)*4];
    tcs[k] = min(max(g, 0), NCH_-1);
  }

  float mv[PPT_], sv[PPT_], vts[PPT_];
  #pragma unroll
  for (int k = 0; k < PPT_; ++k) { mv[k] = -INFINITY; sv[k] = 0.0f; vts[k] = 0.0f; }

  // ---- stuff channels of this group (c = grp, grp+8, ... < 53) ----
  // rolling 1-deep prefetch keeps a load in flight across the lse consume.
  {
    int c = grp;
    if (c < CS_) {
      f2 v = NT_LD((const f2*)(stuff_logit + c*HW_ + pix0));
      for (;;) {
        int cn = c + G_;
        bool more = (cn < CS_);
        f2 vn;
        if (more) vn = NT_LD((const f2*)(stuff_logit + cn*HW_ + pix0));
        NT_ST(v, (f2*)(out + c*HW_ + pix0));
        #pragma unroll
        for (int k = 0; k < PPT_; ++k) {
          lse_update(v[k], mv[k], sv[k]);
          if (c == tcs[k]) vts[k] = v[k];
        }
        if (!more) break;
        v = vn; c = cn;
      }
    }
  }

  // ---- thing channels: 3-pass (mask / zero-burst / active) ----
  unsigned amask = 0u;
  #pragma unroll
  for (int i = 0; i < NTH_G; ++i) {
    int4 u = sbox[cth_start - CS_ + 8*i];
    bool rej = (y < u.x) | (y > u.y) | (xb > u.w) | (xb + PPT_ - 1 < u.z);
    if (!__all(rej)) amask |= (1u << i);
  }
  amask = __builtin_amdgcn_readfirstlane(amask);  // SGPR -> scalar branches
  int zc = NTH_G - __popc(amask);   // wave-uniform
  {
    f2 z = {0.0f, 0.0f};
    for (int i = 0; i < NTH_G; ++i) {
      if (!((amask >> i) & 1u))
        NT_ST(z, (f2*)(out + (cth_start + 8*i)*HW_ + pix0));
    }
  }
  unsigned am = amask;
  while (am) {
    int i = __builtin_ctz(am); am &= am - 1u;
    int cc = cth_start + 8*i;
    NParam p = spar[cc - CS_];
    float vv[PPT_] = {0.0f, 0.0f};
    if (y >= p.cy1 && y < p.cy2 && xb < p.cx2 && xb+PPT_-1 >= p.cx1) {
      f2 t = NT_LD((const f2*)(thing_logit + p.thbase + pix0));
      #pragma unroll
      for (int k = 0; k < PPT_; ++k) {
        int x = xb + k;
        if (x >= p.cx1 && x < p.cx2) vv[k] = t[k];
      }
    }
    if (y >= p.vy_lo && y <= p.vy_hi && xb <= p.vx_hi && xb+PPT_-1 >= p.vx_lo) {
      float srcy = ((float)(y - p.y0b) + 0.5f)*p.sy - 0.5f;
      float fy = floorf(srcy); float ty = srcy - fy;
      int i0 = (int)fminf(fmaxf(fy,        0.0f), (float)(MS_-1));
      int i1 = (int)fminf(fmaxf(fy + 1.0f, 0.0f), (float)(MS_-1));
      const float* r0p = mask_logits + p.mlbase + i0*MS_;
      const float* r1p = mask_logits + p.mlbase + i1*MS_;
      #pragma unroll
      for (int k = 0; k < PPT_; ++k) {
        int x = xb + k;
        if (x >= p.vx_lo && x <= p.vx_hi) {
          float srcx = ((float)(x - p.x0b) + 0.5f)*p.sx - 0.5f;
          float fx = floorf(srcx); float tx = srcx - fx;
          int j0 = (int)fminf(fmaxf(fx,        0.0f), (float)(MS_-1));
          int j1 = (int)fminf(fmaxf(fx + 1.0f, 0.0f), (float)(MS_-1));
          float r0 = r0p[j0]*(1.0f - tx) + r0p[j1]*tx;
          float r1 = r1p[j0]*(1.0f - tx) + r1p[j1]*tx;
          vv[k] += r0*(1.0f - ty) + r1*ty;
        }
      }
    }
    f2 ov = {vv[0], vv[1]};
    NT_ST(ov, (f2*)(out + cc*HW_ + pix0));
    #pragma unroll
    for (int k = 0; k < PPT_; ++k) {
      lse_update(vv[k], mv[k], sv[k]);
      if (cc == tcs[k]) vts[k] = vv[k];
    }
  }

  // merge skipped zero-channels analytically; lp -> LDS
  {
    float zcf = (float)zc;
    #pragma unroll
    for (int k = 0; k < PPT_; ++k) {
      float m = mv[k], s = sv[k];
      if (zc > 0) {
        if (m >= 0.0f) { s = fmaf(zcf, __expf(-m), s); }
        else           { s = fmaf(s, __expf(m), zcf); m = 0.0f; }  // m=-inf ok: s->zcf
      }
      lp_lds[grp][lane*PPT_ + k] = m + __logf(s);
      // exactly one wave owns each pixel's target channel (tcs % 8 == grp)
      if ((tcs[k] & (G_-1)) == grp) vt_lds[lane*PPT_ + k] = vts[k];
    }
  }
  __syncthreads();

  // ---- intra-block combine: threads 0..127, one pixel each ----
  float nll = 0.0f, cnt = 0.0f;
  if (tid < TPX_) {
    int p = blockIdx.x*TPX_ + tid;
    float m = lp_lds[0][tid], s = 1.0f;
    #pragma unroll
    for (int g = 1; g < G_; ++g) {
      float lg = lp_lds[g][tid];
      float d = lg - m;
      float e = __expf(-fabsf(d));
      s = (d > 0.0f) ? fmaf(s, e, 1.0f) : (s + e);
      m = fmaxf(m, lg);
    }
    int yy = p / W_;
    int xx = p - yy*W_;
    int gv = gt[yy*(4*WG_) + xx*4];   // L1/L2-hot (loaded above)
    bool valid = (gv != IGN_);
    nll = valid ? (m + __logf(s) - vt_lds[tid]) : 0.0f;
    cnt = valid ? 1.0f : 0.0f;
  }

  // block reduce (threads >=128 contribute 0)
  for (int off = 32; off >= 1; off >>= 1) {
    nll += __shfl_down(nll, off, 64);
    cnt += __shfl_down(cnt, off, 64);
  }
  int wid = tid >> 6;
  if ((tid & 63) == 0) { red[wid*2] = nll; red[wid*2+1] = cnt; }
  __syncthreads();
  if (tid == 0) {
    float ts = red[0] + red[2], tcn = red[1] + red[3];   // only waves 0-1 nonzero
    AG_ST(&g_part[blockIdx.x*2],     ts);
    AG_ST(&g_part[blockIdx.x*2 + 1], tcn);
    // same-thread order: partial stores must COMPLETE before the ticket
    asm volatile("s_waitcnt vmcnt(0)" ::: "memory");
    unsigned d = __hip_atomic_fetch_add(&g_done, 1u,
                                        __ATOMIC_RELAXED, __HIP_MEMORY_SCOPE_AGENT);
    s_fin = ((d % (unsigned)GX_) == (unsigned)(GX_-1)) ? 1u : 0u;
  }
  __syncthreads();
  if (s_fin) {
    // last block overall: fold GX_=1250 partials, write the loss
    float a = 0.0f, b = 0.0f;
    for (int i = tid; i < GX_; i += BT_) {
      a += AG_LD(&g_part[i*2]);
      b += AG_LD(&g_part[i*2 + 1]);
    }
    for (int off = 32; off >= 1; off >>= 1) {
      a += __shfl_down(a, off, 64);
      b += __shfl_down(b, off, 64);
    }
    if ((tid & 63) == 0) { red[wid*2] = a; red[wid*2+1] = b; }
    __syncthreads();
    if (tid == 0) {
      float ts = 0.0f, tcn = 0.0f;
      #pragma unroll
      for (int i = 0; i < 8; ++i) { ts += red[i*2]; tcn += red[i*2+1]; }
      out[NCH_*HW_] = ts / fmaxf(tcn, 1.0f);   // LOSS_W = 1.0
    }
  }
}

extern "C" void kernel_launch(void* const* d_in, const int* in_sizes, int n_in,
                              void* d_out, int out_size, void* d_ws, size_t ws_size,
                              hipStream_t stream) {
  const float* mask_logits = (const float*)d_in[0];
  const float* stuff_logit = (const float*)d_in[1];
  const float* thing_logit = (const float*)d_in[2];
  const float* bbox        = (const float*)d_in[3];
  const int*   cls_idx     = (const int*)d_in[4];
  const int*   gt          = (const int*)d_in[5];
  float* out = (float*)d_out;

  main_kernel<<<GX_, BT_, 0, stream>>>(mask_logits, stuff_logit, thing_logit,
                                       bbox, cls_idx, gt, out);
}

// Round 14
// 209.818 us; speedup vs baseline: 1.0785x; 1.0199x over previous
//
#include <hip/hip_runtime.h>
#include <math.h>

#define N_   128
#define H_   400
#define W_   400
#define MS_  28
#define CT_  80
#define CS_  53
#define HW_  (H_*W_)
#define NCH_ (CS_ + N_)   // 181
#define WG_  1600
#define IGN_ 255
#define G_   8            // channel groups == waves per block
#define NTH_G 16          // thing channels per group: 128/8 exactly
#define PPT_ 2            // pixels per thread (float2)
#define BT_  512          // 8 waves per block; wave w = channel group w
#define TPX_ 128          // pixels per block (64 lanes * PPT)
#define GX_  (HW_/TPX_)   // 1250 blocks (exact)
#define NSMAX_ 7          // max stuff channels per group

typedef float f2 __attribute__((ext_vector_type(2)));

#define NT_LD(p)    __builtin_nontemporal_load(p)
#define NT_ST(v, p) __builtin_nontemporal_store((v), (p))

struct NParam {
  int vy_lo, vy_hi, vx_lo, vx_hi;   // mask-valid box (inclusive)
  int cy1, cy2, cx1, cx2;           // sem box (y in [cy1,cy2), x in [cx1,cx2))
  float sy, sx;                     // 28/hh, 28/ww
  int y0b, x0b;                     // floor(bbox/4)
  int mlbase, thbase;               // offsets into mask_logits / thing_logit
  int pad0, pad1;                   // 64 B
};

// Device globals. g_done is an EPOCH counter (monotonic, old%GX picks the
// winner) -> no zeroing needed, graph-replay and rocprof-replay safe.
// g_part is fully rewritten each launch before being read; cross-block
// traffic uses agent-scope (cache-bypassing) accesses -> no reliance on
// cross-XCD L2 coherence.
__device__ unsigned int g_done;           // global ticket
__device__ float        g_part[GX_*2];    // per-block (nll,cnt) partials

#define AG_ST(p, v) __hip_atomic_store((p), (v), __ATOMIC_RELAXED, __HIP_MEMORY_SCOPE_AGENT)
#define AG_LD(p)    __hip_atomic_load((p), __ATOMIC_RELAXED, __HIP_MEMORY_SCOPE_AGENT)

__device__ __forceinline__ void lse_update(float v, float& m, float& s) {
  float d = v - m;
  float e = __expf(-fabsf(d));
  s = (d > 0.0f) ? fmaf(s, e, 1.0f) : (s + e);
  m = fmaxf(m, v);
}

// Fused, single-block-per-tile: 8 waves = 8 channel groups (c % 8 == w),
// all covering the SAME 128 pixels; intra-block LDS combine.
// NEW (this round): ALL stuff loads are issued up front (batch of 6-7
// global_load_dwordx2), then the thing-channel bitmask + zero-store burst
// runs while they are in flight, then the values are consumed. Previously
// the burst (pure stores, perfect latency cover) ran AFTER the loads had
// been waited on 1-by-1 -> load latency was exposed every stuff iteration.
__global__ __launch_bounds__(512) void main_kernel(
    const float* __restrict__ mask_logits,
    const float* __restrict__ stuff_logit,
    const float* __restrict__ thing_logit,
    const float* __restrict__ bbox,
    const int*   __restrict__ cls_idx,
    const int*   __restrict__ gt,
    float* __restrict__ out)
{
  __shared__ NParam spar[N_];
  __shared__ int4   sbox[N_];       // superbox = union(sem, mask), inclusive
  __shared__ float  lp_lds[G_][TPX_];
  __shared__ float  vt_lds[TPX_];
  __shared__ float  red[16];
  __shared__ unsigned s_fin;
  int tid = threadIdx.x;
  if (tid < N_) {
    int n = tid;
    float b0 = bbox[4*n+0]*0.25f, b1 = bbox[4*n+1]*0.25f,
          b2 = bbox[4*n+2]*0.25f, b3 = bbox[4*n+3]*0.25f;
    int x0b = (int)floorf(b0), y0b = (int)floorf(b1);
    int x2b = (int)floorf(b2), y2b = (int)floorf(b3);
    int hh = y2b - y0b + 1, ww = x2b - x0b + 1;
    NParam p;
    p.vy_lo = max(y0b, 0); p.vy_hi = min(y2b, H_-1);
    p.vx_lo = max(x0b, 0); p.vx_hi = min(x2b, W_-1);
    p.cy1 = (int)b1; p.cx1 = (int)b0;                 // trunc (positive)
    p.cy2 = (int)(rintf(b3) + 1.0f);                  // jnp.round = RNE
    p.cx2 = (int)(rintf(b2) + 1.0f);
    p.sy = 28.0f / (float)hh; p.sx = 28.0f / (float)ww;
    p.y0b = y0b; p.x0b = x0b;
    int cls = cls_idx[n];
    p.mlbase = (n*CT_ + cls)*(MS_*MS_);
    p.thbase = cls*HW_;
    p.pad0 = 0; p.pad1 = 0;
    spar[n] = p;
    sbox[n] = make_int4(min(p.vy_lo, p.cy1), max(p.vy_hi, p.cy2 - 1),
                        min(p.vx_lo, p.cx1), max(p.vx_hi, p.cx2 - 1));
  }
  __syncthreads();

  int grp  = tid >> 6;              // wave id == channel group
  int lane = tid & 63;
  int pix0 = blockIdx.x*TPX_ + lane*PPT_;
  int y  = pix0 / W_;               // W_ even, pix0 even -> pair shares row
  int xb = pix0 - y*W_;
  // first thing channel of this group: smallest c>=53 with c%8==grp
  int cth_start = CS_ + ((grp - (CS_ & 7)) & 7);
  // stuff channels of this group: grp, grp+8, ... < 53
  int ns = (grp <= 4) ? 7 : 6;      // wave-uniform trip count

  // target channel per pixel
  int tcs[PPT_];
  #pragma unroll
  for (int k = 0; k < PPT_; ++k) {
    int g = gt[y*(4*WG_) + (xb + k)*4];
    tcs[k] = min(max(g, 0), NCH_-1);
  }

  // ---- issue ALL stuff loads up front (stay in flight through the burst) --
  f2 vls[NSMAX_];
  #pragma unroll
  for (int i = 0; i < NSMAX_; ++i) {
    if (i < ns)
      vls[i] = NT_LD((const f2*)(stuff_logit + (grp + 8*i)*HW_ + pix0));
  }

  float mv[PPT_], sv[PPT_], vts[PPT_];
  #pragma unroll
  for (int k = 0; k < PPT_; ++k) { mv[k] = -INFINITY; sv[k] = 0.0f; vts[k] = 0.0f; }

  // ---- thing bitmask (no vmem) + zero-store burst (covers load latency) ----
  unsigned amask = 0u;
  #pragma unroll
  for (int i = 0; i < NTH_G; ++i) {
    int4 u = sbox[cth_start - CS_ + 8*i];
    bool rej = (y < u.x) | (y > u.y) | (xb > u.w) | (xb + PPT_ - 1 < u.z);
    if (!__all(rej)) amask |= (1u << i);
  }
  amask = __builtin_amdgcn_readfirstlane(amask);  // SGPR -> scalar branches
  int zc = NTH_G - __popc(amask);   // wave-uniform
  {
    f2 z = {0.0f, 0.0f};
    for (int i = 0; i < NTH_G; ++i) {
      if (!((amask >> i) & 1u))
        NT_ST(z, (f2*)(out + (cth_start + 8*i)*HW_ + pix0));
    }
  }

  // ---- consume stuff values (loads have had the whole burst to land) ----
  #pragma unroll
  for (int i = 0; i < NSMAX_; ++i) {
    if (i < ns) {
      int c = grp + 8*i;
      NT_ST(vls[i], (f2*)(out + c*HW_ + pix0));
      #pragma unroll
      for (int k = 0; k < PPT_; ++k) {
        lse_update(vls[i][k], mv[k], sv[k]);
        if (c == tcs[k]) vts[k] = vls[i][k];
      }
    }
  }

  // ---- active thing channels (expected ~1-2 per wave) ----
  unsigned am = amask;
  while (am) {
    int i = __builtin_ctz(am); am &= am - 1u;
    int cc = cth_start + 8*i;
    NParam p = spar[cc - CS_];
    float vv[PPT_] = {0.0f, 0.0f};
    if (y >= p.cy1 && y < p.cy2 && xb < p.cx2 && xb+PPT_-1 >= p.cx1) {
      f2 t = NT_LD((const f2*)(thing_logit + p.thbase + pix0));
      #pragma unroll
      for (int k = 0; k < PPT_; ++k) {
        int x = xb + k;
        if (x >= p.cx1 && x < p.cx2) vv[k] = t[k];
      }
    }
    if (y >= p.vy_lo && y <= p.vy_hi && xb <= p.vx_hi && xb+PPT_-1 >= p.vx_lo) {
      float srcy = ((float)(y - p.y0b) + 0.5f)*p.sy - 0.5f;
      float fy = floorf(srcy); float ty = srcy - fy;
      int i0 = (int)fminf(fmaxf(fy,        0.0f), (float)(MS_-1));
      int i1 = (int)fminf(fmaxf(fy + 1.0f, 0.0f), (float)(MS_-1));
      const float* r0p = mask_logits + p.mlbase + i0*MS_;
      const float* r1p = mask_logits + p.mlbase + i1*MS_;
      #pragma unroll
      for (int k = 0; k < PPT_; ++k) {
        int x = xb + k;
        if (x >= p.vx_lo && x <= p.vx_hi) {
          float srcx = ((float)(x - p.x0b) + 0.5f)*p.sx - 0.5f;
          float fx = floorf(srcx); float tx = srcx - fx;
          int j0 = (int)fminf(fmaxf(fx,        0.0f), (float)(MS_-1));
          int j1 = (int)fminf(fmaxf(fx + 1.0f, 0.0f), (float)(MS_-1));
          float r0 = r0p[j0]*(1.0f - tx) + r0p[j1]*tx;
          float r1 = r1p[j0]*(1.0f - tx) + r1p[j1]*tx;
          vv[k] += r0*(1.0f - ty) + r1*ty;
        }
      }
    }
    f2 ov = {vv[0], vv[1]};
    NT_ST(ov, (f2*)(out + cc*HW_ + pix0));
    #pragma unroll
    for (int k = 0; k < PPT_; ++k) {
      lse_update(vv[k], mv[k], sv[k]);
      if (cc == tcs[k]) vts[k] = vv[k];
    }
  }

  // merge skipped zero-channels analytically; lp -> LDS
  {
    float zcf = (float)zc;
    #pragma unroll
    for (int k = 0; k < PPT_; ++k) {
      float m = mv[k], s = sv[k];
      if (zc > 0) {
        if (m >= 0.0f) { s = fmaf(zcf, __expf(-m), s); }
        else           { s = fmaf(s, __expf(m), zcf); m = 0.0f; }  // m=-inf ok: s->zcf
      }
      lp_lds[grp][lane*PPT_ + k] = m + __logf(s);
      // exactly one wave owns each pixel's target channel (tcs % 8 == grp)
      if ((tcs[k] & (G_-1)) == grp) vt_lds[lane*PPT_ + k] = vts[k];
    }
  }
  __syncthreads();

  // ---- intra-block combine: threads 0..127, one pixel each ----
  float nll = 0.0f, cnt = 0.0f;
  if (tid < TPX_) {
    int p = blockIdx.x*TPX_ + tid;
    float m = lp_lds[0][tid], s = 1.0f;
    #pragma unroll
    for (int g = 1; g < G_; ++g) {
      float lg = lp_lds[g][tid];
      float d = lg - m;
      float e = __expf(-fabsf(d));
      s = (d > 0.0f) ? fmaf(s, e, 1.0f) : (s + e);
      m = fmaxf(m, lg);
    }
    int yy = p / W_;
    int xx = p - yy*W_;
    int gv = gt[yy*(4*WG_) + xx*4];   // L1/L2-hot (loaded above)
    bool valid = (gv != IGN_);
    nll = valid ? (m + __logf(s) - vt_lds[tid]) : 0.0f;
    cnt = valid ? 1.0f : 0.0f;
  }

  // block reduce (threads >=128 contribute 0)
  for (int off = 32; off >= 1; off >>= 1) {
    nll += __shfl_down(nll, off, 64);
    cnt += __shfl_down(cnt, off, 64);
  }
  int wid = tid >> 6;
  if ((tid & 63) == 0) { red[wid*2] = nll; red[wid*2+1] = cnt; }
  __syncthreads();
  if (tid == 0) {
    float ts = red[0] + red[2], tcn = red[1] + red[3];   // only waves 0-1 nonzero
    AG_ST(&g_part[blockIdx.x*2],     ts);
    AG_ST(&g_part[blockIdx.x*2 + 1], tcn);
    // same-thread order: partial stores must COMPLETE before the ticket
    asm volatile("s_waitcnt vmcnt(0)" ::: "memory");
    unsigned d = __hip_atomic_fetch_add(&g_done, 1u,
                                        __ATOMIC_RELAXED, __HIP_MEMORY_SCOPE_AGENT);
    s_fin = ((d % (unsigned)GX_) == (unsigned)(GX_-1)) ? 1u : 0u;
  }
  __syncthreads();
  if (s_fin) {
    // last block overall: fold GX_=1250 partials, write the loss
    float a = 0.0f, b = 0.0f;
    for (int i = tid; i < GX_; i += BT_) {
      a += AG_LD(&g_part[i*2]);
      b += AG_LD(&g_part[i*2 + 1]);
    }
    for (int off = 32; off >= 1; off >>= 1) {
      a += __shfl_down(a, off, 64);
      b += __shfl_down(b, off, 64);
    }
    if ((tid & 63) == 0) { red[wid*2] = a; red[wid*2+1] = b; }
    __syncthreads();
    if (tid == 0) {
      float ts = 0.0f, tcn = 0.0f;
      #pragma unroll
      for (int i = 0; i < 8; ++i) { ts += red[i*2]; tcn += red[i*2+1]; }
      out[NCH_*HW_] = ts / fmaxf(tcn, 1.0f);   // LOSS_W = 1.0
    }
  }
}

extern "C" void kernel_launch(void* const* d_in, const int* in_sizes, int n_in,
                              void* d_out, int out_size, void* d_ws, size_t ws_size,
                              hipStream_t stream) {
  const float* mask_logits = (const float*)d_in[0];
  const float* stuff_logit = (const float*)d_in[1];
  const float* thing_logit = (const float*)d_in[2];
  const float* bbox        = (const float*)d_in[3];
  const int*   cls_idx     = (const int*)d_in[4];
  const int*   gt          = (const int*)d_in[5];
  float* out = (float*)d_out;

  main_kernel<<<GX_, BT_, 0, stream>>>(mask_logits, stuff_logit, thing_logit,
                                       bbox, cls_idx, gt, out);
}